// Round 2
// baseline (1071.990 us; speedup 1.0000x reference)
//
#include <hip/hip_runtime.h>
#include <cstdint>
#include <cstddef>

// PhasorLayerLinear fused pipeline for MI355X (gfx950).
//
//   K0 : weight prep  (value_W -> f16; g-folded out_W -> f16; key/query W -> f16 hi/lo; c1,c2)
//   K1 : kq phases    (3-pass hi/lo f16 MFMA for accuracy) -> s[row]
//   K2 : V = x @ Wv^T (1-pass f16 MFMA) -> Vh (f16) + per-row partial sums/sumsq
//   K2b: per-row alpha/beta from s + stats   (LN folded into scalars)
//   K3 : out = x + alpha*(Vh @ (g.out_W)^T) + beta*c1 + c2   (1-pass f16 MFMA)
//
// Math: LayerNorm is scale-invariant per row, so the phasor gain collapses to
// per-row scalars: s = gain*mean(align); alpha = s*rsqrt(s^2*var_V + eps);
// beta = -alpha*mu_V; ln affine folds into Wo (g element-wise) + rank-1 c1/c2.

typedef _Float16 f16;
typedef _Float16 f16x4 __attribute__((ext_vector_type(4)));
typedef _Float16 f16x8 __attribute__((ext_vector_type(8)));
typedef float    f32x4 __attribute__((ext_vector_type(4)));

#define PI_F 3.14159265358979323846f

// CK-style address-space bridging (direct C-style casts between address
// spaces can be rejected by clang; integer round-trip is always legal).
typedef const __attribute__((address_space(1))) void* gptr_t;
typedef __attribute__((address_space(3))) void* lptr_t;

__device__ __forceinline__ void gld16(const void* g, void* l) {
  __builtin_amdgcn_global_load_lds((gptr_t)(uintptr_t)g, (lptr_t)(uint32_t)(uintptr_t)l,
                                   16, 0, 0);
}

__device__ __forceinline__ f32x4 mfma16(f16x8 a, f16x8 b, f32x4 c) {
  return __builtin_amdgcn_mfma_f32_16x16x32_f16(a, b, c, 0, 0, 0);
}

// LDS tile is [rows][64] f16, row-major. off = kk*32 + (lane>>4)*8.
__device__ __forceinline__ f16x8 ldfrag(const f16* L, int row, int off) {
  return *(const f16x8*)(L + row * 64 + off);
}

// ---------------- K0: weight prep ----------------
__global__ void __launch_bounds__(256) k0_prep(
    const float* __restrict__ value_W, const float* __restrict__ out_W,
    const float* __restrict__ key_W,   const float* __restrict__ query_W,
    const float* __restrict__ ln_g,    const float* __restrict__ ln_b,
    const float* __restrict__ out_b,
    f16* __restrict__ Wv, f16* __restrict__ Wo,
    f16* __restrict__ kqh, f16* __restrict__ kql,
    float* __restrict__ c1, float* __restrict__ c2)
{
  __shared__ float r1[256];
  __shared__ float r2[256];
  int t = threadIdx.x;
  int blk = blockIdx.x;
  if (blk < 1024) {
    int n = blk;
    float4 v = ((const float4*)(value_W + (size_t)n * 1024))[t];
    float4 o = ((const float4*)(out_W   + (size_t)n * 1024))[t];
    float4 g = ((const float4*)ln_g)[t];
    float4 b = ((const float4*)ln_b)[t];
    f16x4 vh = {(f16)v.x, (f16)v.y, (f16)v.z, (f16)v.w};
    ((f16x4*)(Wv + (size_t)n * 1024))[t] = vh;
    float gx = o.x * g.x, gy = o.y * g.y, gz = o.z * g.z, gw = o.w * g.w;
    f16x4 oh = {(f16)gx, (f16)gy, (f16)gz, (f16)gw};
    ((f16x4*)(Wo + (size_t)n * 1024))[t] = oh;
    r1[t] = gx + gy + gz + gw;                                // sum g_k * Wo[n][k]
    r2[t] = o.x*b.x + o.y*b.y + o.z*b.z + o.w*b.w;            // sum b_k * Wo[n][k]
    __syncthreads();
    for (int off = 128; off > 0; off >>= 1) {
      if (t < off) { r1[t] += r1[t + off]; r2[t] += r2[t + off]; }
      __syncthreads();
    }
    if (t == 0) { c1[n] = r1[0]; c2[n] = r2[0] + out_b[n]; }
  } else {
    int r = blk - 1024;  // 0..15 key planes, 16..31 query planes
    const float* src = (r < 16) ? (key_W + (size_t)r * 1024)
                                : (query_W + (size_t)(r - 16) * 1024);
    float4 v = ((const float4*)src)[t];
    f16 h0 = (f16)v.x, h1 = (f16)v.y, h2 = (f16)v.z, h3 = (f16)v.w;
    f16x4 hv = {h0, h1, h2, h3};
    f16x4 lv = {(f16)(v.x - (float)h0), (f16)(v.y - (float)h1),
                (f16)(v.z - (float)h2), (f16)(v.w - (float)h3)};
    ((f16x4*)(kqh + (size_t)r * 1024))[t] = hv;
    ((f16x4*)(kql + (size_t)r * 1024))[t] = lv;
  }
}

// ---------------- staging helpers ----------------
// reg-stage 128x64 fp32 x tile -> f16 hi LDS tile (convert in flight)
__device__ __forceinline__ void stage_x_h(const float* __restrict__ xg, int row0, int kt,
                                          f16* Ah, int t)
{
  const float* base = xg + (size_t)row0 * 1024 + kt * 64;
#pragma unroll
  for (int it = 0; it < 8; ++it) {
    int cf = it * 256 + t;
    int r = cf >> 4, ci = cf & 15;
    float4 v = *(const float4*)(base + (size_t)r * 1024 + ci * 4);
    f16x4 h = {(f16)v.x, (f16)v.y, (f16)v.z, (f16)v.w};
    *(f16x4*)(Ah + r * 64 + ci * 4) = h;
  }
}

// reg-stage 128x64 fp32 x tile -> f16 hi + lo LDS tiles (lossless to ~2^-22)
__device__ __forceinline__ void stage_x_hl(const float* __restrict__ xg, int row0, int kt,
                                           f16* Ah, f16* Al, int t)
{
  const float* base = xg + (size_t)row0 * 1024 + kt * 64;
#pragma unroll
  for (int it = 0; it < 8; ++it) {
    int cf = it * 256 + t;
    int r = cf >> 4, ci = cf & 15;
    float4 v = *(const float4*)(base + (size_t)r * 1024 + ci * 4);
    f16 h0 = (f16)v.x, h1 = (f16)v.y, h2 = (f16)v.z, h3 = (f16)v.w;
    f16x4 h = {h0, h1, h2, h3};
    f16x4 lo = {(f16)(v.x - (float)h0), (f16)(v.y - (float)h1),
                (f16)(v.z - (float)h2), (f16)(v.w - (float)h3)};
    *(f16x4*)(Ah + r * 64 + ci * 4) = h;
    *(f16x4*)(Al + r * 64 + ci * 4) = lo;
  }
}

// async-stage an [nrows x 64] f16 tile (global row stride 1024) via global_load_lds w=16
// LDS dest is linear in thread id => wave-uniform base + lane*16B (HW requirement).
__device__ __forceinline__ void stage_w(const f16* __restrict__ wg, int n0, int kt,
                                        f16* Bt, int t, int nchunk)
{
  for (int c = t; c < nchunk; c += 256) {
    int r = c >> 3, ci = c & 7;
    gld16(wg + (size_t)(n0 + r) * 1024 + kt * 64 + ci * 8, Bt + c * 8);
  }
}

// ---------------- K1: key/query phases -> s[row] ----------------
// 3-pass hi/lo split (a_h*b_h + a_h*b_l + a_l*b_h): the rsqrt(eps) knife-edge
// amplifies s-errors by up to ~316x, so the phase dots need ~1e-5 accuracy.
__global__ void __launch_bounds__(256) k1_kq(
    const float* __restrict__ x,
    const f16* __restrict__ kqh, const f16* __restrict__ kql,
    const float* __restrict__ key_b, const float* __restrict__ query_b,
    float* __restrict__ sarr)
{
  __shared__ __align__(16) f16 Ah[128 * 64];
  __shared__ __align__(16) f16 Al[128 * 64];
  __shared__ __align__(16) f16 Bh[32 * 64];
  __shared__ __align__(16) f16 Bl[32 * 64];
  int t = threadIdx.x, bm = blockIdx.x;
  int w = t >> 6, l = t & 63, lp = l & 15, lhi = l >> 4;
  f32x4 z = {0.f, 0.f, 0.f, 0.f};
  f32x4 acc[2][2];
  acc[0][0] = z; acc[0][1] = z; acc[1][0] = z; acc[1][1] = z;

  for (int kt = 0; kt < 16; ++kt) {
    stage_x_hl(x, bm * 128, kt, Ah, Al, t);
    stage_w(kqh, 0, kt, Bh, t, 256);
    stage_w(kql, 0, kt, Bl, t, 256);
    __syncthreads();
#pragma unroll
    for (int kk = 0; kk < 2; ++kk) {
      int off = kk * 32 + lhi * 8;
      f16x8 a_h[2], a_l[2], b_h[2], b_l[2];
#pragma unroll
      for (int m = 0; m < 2; ++m) {
        int r = w * 32 + m * 16 + lp;
        a_h[m] = ldfrag(Ah, r, off);
        a_l[m] = ldfrag(Al, r, off);
      }
#pragma unroll
      for (int n = 0; n < 2; ++n) {
        int r = n * 16 + lp;
        b_h[n] = ldfrag(Bh, r, off);
        b_l[n] = ldfrag(Bl, r, off);
      }
#pragma unroll
      for (int m = 0; m < 2; ++m)
#pragma unroll
        for (int n = 0; n < 2; ++n) {
          acc[m][n] = mfma16(a_h[m], b_h[n], acc[m][n]);
          acc[m][n] = mfma16(a_h[m], b_l[n], acc[m][n]);
          acc[m][n] = mfma16(a_l[m], b_h[n], acc[m][n]);
        }
    }
    __syncthreads();
  }

  // epilogue: lane lp = plane index; cols 0..15 key dots, 16..31 query dots
  float kb = key_b[lp], qb = query_b[lp];
#pragma unroll
  for (int m = 0; m < 2; ++m) {
#pragma unroll
    for (int j = 0; j < 4; ++j) {
      float kd = acc[m][0][j] + kb;
      float qd = acc[m][1][j] + qb;
      float av = cosf((tanhf(kd) - tanhf(qd)) * PI_F);
      av += __shfl_xor(av, 1);
      av += __shfl_xor(av, 2);
      av += __shfl_xor(av, 4);
      av += __shfl_xor(av, 8);
      if (lp == 0) {
        int row = bm * 128 + w * 32 + m * 16 + lhi * 4 + j;
        float res = av * (1.f / 16.f);                    // mean(align)
        float zz = res + 0.5f;
        float gain = fmaxf(zz, 0.f) + log1pf(expf(-fabsf(zz)));  // softplus
        sarr[row] = gain * res;                           // s = gain*sum(align)/16
      }
    }
  }
}

// ---------------- K2: V = x @ value_W^T (+bias) -> Vh + row stats ----------------
__global__ void __launch_bounds__(256) k2_vgemm(
    const float* __restrict__ x, const f16* __restrict__ Wv,
    const float* __restrict__ value_b,
    f16* __restrict__ Vh, float* __restrict__ part)
{
  __shared__ __align__(16) f16 Ah[128 * 64];
  __shared__ __align__(16) f16 Bh[128 * 64];
  int t = threadIdx.x;
  int bn = blockIdx.x, bm = blockIdx.y;
  int w = t >> 6, l = t & 63, lp = l & 15, lhi = l >> 4;
  int wr = w >> 1, wc = w & 1;
  f32x4 z = {0.f, 0.f, 0.f, 0.f};
  f32x4 acc[4][4];
#pragma unroll
  for (int m = 0; m < 4; ++m)
#pragma unroll
    for (int n = 0; n < 4; ++n) acc[m][n] = z;

  for (int kt = 0; kt < 16; ++kt) {
    stage_x_h(x, bm * 128, kt, Ah, t);
    stage_w(Wv, bn * 128, kt, Bh, t, 1024);
    __syncthreads();
#pragma unroll
    for (int kk = 0; kk < 2; ++kk) {
      int off = kk * 32 + lhi * 8;
      f16x8 af[4], bf[4];
#pragma unroll
      for (int m = 0; m < 4; ++m) af[m] = ldfrag(Ah, wr * 64 + m * 16 + lp, off);
#pragma unroll
      for (int n = 0; n < 4; ++n) bf[n] = ldfrag(Bh, wc * 64 + n * 16 + lp, off);
#pragma unroll
      for (int m = 0; m < 4; ++m)
#pragma unroll
        for (int n = 0; n < 4; ++n)
          acc[m][n] = mfma16(af[m], bf[n], acc[m][n]);
    }
    __syncthreads();
  }

  int col0 = bn * 128 + wc * 64;
  float vb[4];
#pragma unroll
  for (int n = 0; n < 4; ++n) vb[n] = value_b[col0 + n * 16 + lp];
#pragma unroll
  for (int m = 0; m < 4; ++m) {
#pragma unroll
    for (int j = 0; j < 4; ++j) {
      int row = bm * 128 + wr * 64 + m * 16 + lhi * 4 + j;
      float sv = 0.f, sq = 0.f;
#pragma unroll
      for (int n = 0; n < 4; ++n) {
        float v = acc[m][n][j] + vb[n];
        Vh[(size_t)row * 1024 + col0 + n * 16 + lp] = (f16)v;
        sv += v; sq += v * v;
      }
      // 16 lanes (same row, 16 cols each covering n*16 span) -> 64-col partial
      sv += __shfl_xor(sv, 1); sq += __shfl_xor(sq, 1);
      sv += __shfl_xor(sv, 2); sq += __shfl_xor(sq, 2);
      sv += __shfl_xor(sv, 4); sq += __shfl_xor(sq, 4);
      sv += __shfl_xor(sv, 8); sq += __shfl_xor(sq, 8);
      if (lp == 0) {
        size_t idx = ((size_t)row * 16 + bn * 2 + wc) * 2;
        part[idx] = sv;
        part[idx + 1] = sq;
      }
    }
  }
}

// ---------------- K2b: per-row alpha/beta ----------------
__global__ void __launch_bounds__(256) k2b_ab(
    const float* __restrict__ part, const float* __restrict__ sarr,
    float* __restrict__ alpha, float* __restrict__ beta)
{
  int row = blockIdx.x * 256 + threadIdx.x;
  const float4* p = (const float4*)(part + (size_t)row * 32);
  float sv = 0.f, sq = 0.f;
#pragma unroll
  for (int i = 0; i < 8; ++i) { float4 q = p[i]; sv += q.x + q.z; sq += q.y + q.w; }
  float mu  = sv * (1.f / 1024.f);
  float var = sq * (1.f / 1024.f) - mu * mu;       // row var of V
  float s = sarr[row];
  float tt = rsqrtf(s * s * var + 1e-5f);          // rsqrt(var_P + eps), var_P = s^2 var_V
  float a = s * tt;
  alpha[row] = a;
  beta[row]  = -a * mu;
}

// ---------------- K3: out = x + alpha*(Vh @ Wo^T) + beta*c1 + c2 ----------------
__global__ void __launch_bounds__(256) k3_out(
    const f16* __restrict__ Vh, const f16* __restrict__ Wo,
    const float* __restrict__ x,
    const float* __restrict__ alpha, const float* __restrict__ beta,
    const float* __restrict__ c1, const float* __restrict__ c2,
    float* __restrict__ out)
{
  __shared__ __align__(16) f16 Ah[128 * 64];
  __shared__ __align__(16) f16 Bh[128 * 64];
  int t = threadIdx.x;
  int bn = blockIdx.x, bm = blockIdx.y;
  int w = t >> 6, l = t & 63, lp = l & 15, lhi = l >> 4;
  int wr = w >> 1, wc = w & 1;
  f32x4 z = {0.f, 0.f, 0.f, 0.f};
  f32x4 acc[4][4];
#pragma unroll
  for (int m = 0; m < 4; ++m)
#pragma unroll
    for (int n = 0; n < 4; ++n) acc[m][n] = z;

  for (int kt = 0; kt < 16; ++kt) {
    stage_w(Vh, bm * 128, kt, Ah, t, 1024);
    stage_w(Wo, bn * 128, kt, Bh, t, 1024);
    __syncthreads();
#pragma unroll
    for (int kk = 0; kk < 2; ++kk) {
      int off = kk * 32 + lhi * 8;
      f16x8 af[4], bf[4];
#pragma unroll
      for (int m = 0; m < 4; ++m) af[m] = ldfrag(Ah, wr * 64 + m * 16 + lp, off);
#pragma unroll
      for (int n = 0; n < 4; ++n) bf[n] = ldfrag(Bh, wc * 64 + n * 16 + lp, off);
#pragma unroll
      for (int m = 0; m < 4; ++m)
#pragma unroll
        for (int n = 0; n < 4; ++n)
          acc[m][n] = mfma16(af[m], bf[n], acc[m][n]);
    }
    __syncthreads();
  }

  int col0 = bn * 128 + wc * 64;
  float c1v[4], c2v[4];
#pragma unroll
  for (int n = 0; n < 4; ++n) {
    c1v[n] = c1[col0 + n * 16 + lp];
    c2v[n] = c2[col0 + n * 16 + lp];
  }
#pragma unroll
  for (int m = 0; m < 4; ++m) {
#pragma unroll
    for (int j = 0; j < 4; ++j) {
      int row = bm * 128 + wr * 64 + m * 16 + lhi * 4 + j;
      float av = alpha[row], bv = beta[row];
      const float* xr = x + (size_t)row * 1024;
      float* orow = out + (size_t)row * 1024;
#pragma unroll
      for (int n = 0; n < 4; ++n) {
        int c = col0 + n * 16 + lp;
        orow[c] = xr[c] + av * acc[m][n][j] + bv * c1v[n] + c2v[n];
      }
    }
  }
}

// ---------------- launch ----------------
extern "C" void kernel_launch(void* const* d_in, const int* in_sizes, int n_in,
                              void* d_out, int out_size, void* d_ws, size_t ws_size,
                              hipStream_t stream)
{
  const float* x       = (const float*)d_in[0];
  const float* key_W   = (const float*)d_in[1];
  const float* key_b   = (const float*)d_in[2];
  const float* query_W = (const float*)d_in[3];
  const float* query_b = (const float*)d_in[4];
  const float* value_W = (const float*)d_in[5];
  const float* value_b = (const float*)d_in[6];
  const float* ln_g    = (const float*)d_in[7];
  const float* ln_b    = (const float*)d_in[8];
  const float* out_W   = (const float*)d_in[9];
  const float* out_b   = (const float*)d_in[10];
  float* out = (float*)d_out;

  // workspace layout (144 MB total)
  char* ws = (char*)d_ws;
  f16*   Wv    = (f16*)(ws);                                  //   2 MB
  f16*   Wo    = (f16*)(ws + (2u << 20));                     //   2 MB (g-folded)
  f16*   kqh   = (f16*)(ws + (4u << 20));                     //  64 KB
  f16*   kql   = (f16*)(ws + (4u << 20) + (64u << 10));       //  64 KB
  float* c1    = (float*)(ws + (4u << 20) + (128u << 10));    //   4 KB
  float* c2    = (float*)(ws + (4u << 20) + (132u << 10));    //   4 KB
  float* sarr  = (float*)(ws + (5u << 20));                   // 256 KB
  float* alpha = (float*)(ws + (5u << 20) + (256u << 10));    // 256 KB
  float* beta  = (float*)(ws + (5u << 20) + (512u << 10));    // 256 KB
  float* part  = (float*)(ws + (6u << 20));                   //   8 MB
  f16*   Vh    = (f16*)(ws + (16u << 20));                    // 128 MB

  k0_prep<<<dim3(1056), dim3(256), 0, stream>>>(value_W, out_W, key_W, query_W,
                                                ln_g, ln_b, out_b,
                                                Wv, Wo, kqh, kql, c1, c2);
  k1_kq<<<dim3(512), dim3(256), 0, stream>>>(x, kqh, kql, key_b, query_b, sarr);
  k2_vgemm<<<dim3(8, 512), dim3(256), 0, stream>>>(x, Wv, value_b, Vh, part);
  k2b_ab<<<dim3(256), dim3(256), 0, stream>>>(part, sarr, alpha, beta);
  k3_out<<<dim3(8, 512), dim3(256), 0, stream>>>(Vh, Wo, x, alpha, beta, c1, c2, out);
}

// Round 4
// 1000.653 us; speedup vs baseline: 1.0713x; 1.0713x over previous
//
#include <hip/hip_runtime.h>
#include <cstdint>
#include <cstddef>

// PhasorLayerLinear fused pipeline for MI355X (gfx950).
//
//   K0 : weight prep  (value_W -> f16; g-folded out_W -> f16; key/query W -> f16 hi/lo; c1,c2)
//   K1 : kq phases    (3-pass hi/lo f16 MFMA) -> s[row]; ALSO emits xh = f16(x) byproduct
//   K2 : V = xh @ Wv^T (pure m97 structure: both operands via global_load_lds w=16)
//   K2b: per-row alpha/beta from s + stats   (LN folded into scalars)
//   K3 : out = x + alpha*(Vh @ (g.out_W)^T) + beta*c1 + c2
//
// Math: LayerNorm is scale-invariant per row, so the phasor gain collapses to
// per-row scalars: s = gain*mean(align); alpha = s*rsqrt(s^2*var_V + eps);
// beta = -alpha*mu_V; ln affine folds into Wo (g element-wise) + rank-1 c1/c2.
//
// R2 post-mortem: K2 at 346us was reg-staging-bound (fp32->f16 cvt+ds_write on
// critical path) + 4x HBM over-fetch of x (1.06GB vs 260MB ideal; L3 thrash,
// same-panel blocks scattered across XCDs). Fix: xh materialized once in K1;
// K2/K3 use async gload_lds only + chunked XCD swizzle (same-panel blocks
// consecutive on one XCD). R3 never ran (GPU timeout); this round adds the
// swizzle to the fallback K2 as well.

typedef _Float16 f16;
typedef _Float16 f16x4 __attribute__((ext_vector_type(4)));
typedef _Float16 f16x8 __attribute__((ext_vector_type(8)));
typedef float    f32x4 __attribute__((ext_vector_type(4)));

#define PI_F 3.14159265358979323846f

// CK-style address-space bridging (integer round-trip is always legal).
typedef const __attribute__((address_space(1))) void* gptr_t;
typedef __attribute__((address_space(3))) void* lptr_t;

__device__ __forceinline__ void gld16(const void* g, void* l) {
  __builtin_amdgcn_global_load_lds((gptr_t)(uintptr_t)g, (lptr_t)(uint32_t)(uintptr_t)l,
                                   16, 0, 0);
}

__device__ __forceinline__ f32x4 mfma16(f16x8 a, f16x8 b, f32x4 c) {
  return __builtin_amdgcn_mfma_f32_16x16x32_f16(a, b, c, 0, 0, 0);
}

// LDS tile is [rows][64] f16, row-major. off = kk*32 + (lane>>4)*8.
__device__ __forceinline__ f16x8 ldfrag(const f16* L, int row, int off) {
  return *(const f16x8*)(L + row * 64 + off);
}

// chunked XCD swizzle (nwg % 8 == 0): XCD (bid%8) owns a contiguous swz chunk;
// within a chunk, each run of 8 swz values shares bm (one A-panel) and sweeps
// all 8 bn column-blocks -> panel read once per XCD L2, weights L2-resident.
__device__ __forceinline__ int xcd_swz(int bid, int nwg) {
  return (bid & 7) * (nwg >> 3) + (bid >> 3);
}

// ---------------- K0: weight prep ----------------
__global__ void __launch_bounds__(256) k0_prep(
    const float* __restrict__ value_W, const float* __restrict__ out_W,
    const float* __restrict__ key_W,   const float* __restrict__ query_W,
    const float* __restrict__ ln_g,    const float* __restrict__ ln_b,
    const float* __restrict__ out_b,
    f16* __restrict__ Wv, f16* __restrict__ Wo,
    f16* __restrict__ kqh, f16* __restrict__ kql,
    float* __restrict__ c1, float* __restrict__ c2)
{
  __shared__ float r1[256];
  __shared__ float r2[256];
  int t = threadIdx.x;
  int blk = blockIdx.x;
  if (blk < 1024) {
    int n = blk;
    float4 v = ((const float4*)(value_W + (size_t)n * 1024))[t];
    float4 o = ((const float4*)(out_W   + (size_t)n * 1024))[t];
    float4 g = ((const float4*)ln_g)[t];
    float4 b = ((const float4*)ln_b)[t];
    f16x4 vh = {(f16)v.x, (f16)v.y, (f16)v.z, (f16)v.w};
    ((f16x4*)(Wv + (size_t)n * 1024))[t] = vh;
    float gx = o.x * g.x, gy = o.y * g.y, gz = o.z * g.z, gw = o.w * g.w;
    f16x4 oh = {(f16)gx, (f16)gy, (f16)gz, (f16)gw};
    ((f16x4*)(Wo + (size_t)n * 1024))[t] = oh;
    r1[t] = gx + gy + gz + gw;                                // sum g_k * Wo[n][k]
    r2[t] = o.x*b.x + o.y*b.y + o.z*b.z + o.w*b.w;            // sum b_k * Wo[n][k]
    __syncthreads();
    for (int off = 128; off > 0; off >>= 1) {
      if (t < off) { r1[t] += r1[t + off]; r2[t] += r2[t + off]; }
      __syncthreads();
    }
    if (t == 0) { c1[n] = r1[0]; c2[n] = r2[0] + out_b[n]; }
  } else {
    int r = blk - 1024;  // 0..15 key planes, 16..31 query planes
    const float* src = (r < 16) ? (key_W + (size_t)r * 1024)
                                : (query_W + (size_t)(r - 16) * 1024);
    float4 v = ((const float4*)src)[t];
    f16 h0 = (f16)v.x, h1 = (f16)v.y, h2 = (f16)v.z, h3 = (f16)v.w;
    f16x4 hv = {h0, h1, h2, h3};
    f16x4 lv = {(f16)(v.x - (float)h0), (f16)(v.y - (float)h1),
                (f16)(v.z - (float)h2), (f16)(v.w - (float)h3)};
    ((f16x4*)(kqh + (size_t)r * 1024))[t] = hv;
    ((f16x4*)(kql + (size_t)r * 1024))[t] = lv;
  }
}

// ---------------- staging helpers ----------------
// reg-stage 128x64 fp32 x tile -> f16 hi LDS tile (fallback path only)
__device__ __forceinline__ void stage_x_h(const float* __restrict__ xg, int row0, int kt,
                                          f16* Ah, int t)
{
  const float* base = xg + (size_t)row0 * 1024 + kt * 64;
#pragma unroll
  for (int it = 0; it < 8; ++it) {
    int cf = it * 256 + t;
    int r = cf >> 4, ci = cf & 15;
    float4 v = *(const float4*)(base + (size_t)r * 1024 + ci * 4);
    f16x4 h = {(f16)v.x, (f16)v.y, (f16)v.z, (f16)v.w};
    *(f16x4*)(Ah + r * 64 + ci * 4) = h;
  }
}

// reg-stage 128x64 fp32 x tile -> f16 hi + lo LDS tiles; optionally emit hi to global
__device__ __forceinline__ void stage_x_hl(const float* __restrict__ xg,
                                           f16* __restrict__ xh_out,
                                           int row0, int kt,
                                           f16* Ah, f16* Al, int t)
{
  const float* base = xg + (size_t)row0 * 1024 + kt * 64;
  f16* obase = xh_out ? (xh_out + (size_t)row0 * 1024 + kt * 64) : nullptr;
#pragma unroll
  for (int it = 0; it < 8; ++it) {
    int cf = it * 256 + t;
    int r = cf >> 4, ci = cf & 15;
    float4 v = *(const float4*)(base + (size_t)r * 1024 + ci * 4);
    f16 h0 = (f16)v.x, h1 = (f16)v.y, h2 = (f16)v.z, h3 = (f16)v.w;
    f16x4 h = {h0, h1, h2, h3};
    f16x4 lo = {(f16)(v.x - (float)h0), (f16)(v.y - (float)h1),
                (f16)(v.z - (float)h2), (f16)(v.w - (float)h3)};
    *(f16x4*)(Ah + r * 64 + ci * 4) = h;
    *(f16x4*)(Al + r * 64 + ci * 4) = lo;
    if (obase) *(f16x4*)(obase + (size_t)r * 1024 + ci * 4) = h;
  }
}

// async-stage an [nrows x 64] f16 tile (global row stride 1024) via global_load_lds w=16
// LDS dest is linear in thread id => wave-uniform base + lane*16B (HW requirement).
__device__ __forceinline__ void stage_w(const f16* __restrict__ wg, int n0, int kt,
                                        f16* Bt, int t, int nchunk)
{
  for (int c = t; c < nchunk; c += 256) {
    int r = c >> 3, ci = c & 7;
    gld16(wg + (size_t)(n0 + r) * 1024 + kt * 64 + ci * 8, Bt + c * 8);
  }
}

// ---------------- K1: key/query phases -> s[row] (+ xh byproduct) ----------------
// 3-pass hi/lo split (a_h*b_h + a_h*b_l + a_l*b_h): the rsqrt(eps) knife-edge
// amplifies s-errors by up to ~316x, so the phase dots need ~1e-5 accuracy.
__global__ void __launch_bounds__(256) k1_kq(
    const float* __restrict__ x, f16* __restrict__ xh_out,
    const f16* __restrict__ kqh, const f16* __restrict__ kql,
    const float* __restrict__ key_b, const float* __restrict__ query_b,
    float* __restrict__ sarr)
{
  __shared__ __align__(16) f16 Ah[128 * 64];
  __shared__ __align__(16) f16 Al[128 * 64];
  __shared__ __align__(16) f16 Bh[32 * 64];
  __shared__ __align__(16) f16 Bl[32 * 64];
  int t = threadIdx.x, bm = blockIdx.x;
  int w = t >> 6, l = t & 63, lp = l & 15, lhi = l >> 4;
  f32x4 z = {0.f, 0.f, 0.f, 0.f};
  f32x4 acc[2][2];
  acc[0][0] = z; acc[0][1] = z; acc[1][0] = z; acc[1][1] = z;

  for (int kt = 0; kt < 16; ++kt) {
    stage_x_hl(x, xh_out, bm * 128, kt, Ah, Al, t);
    stage_w(kqh, 0, kt, Bh, t, 256);
    stage_w(kql, 0, kt, Bl, t, 256);
    __syncthreads();
#pragma unroll
    for (int kk = 0; kk < 2; ++kk) {
      int off = kk * 32 + lhi * 8;
      f16x8 a_h[2], a_l[2], b_h[2], b_l[2];
#pragma unroll
      for (int m = 0; m < 2; ++m) {
        int r = w * 32 + m * 16 + lp;
        a_h[m] = ldfrag(Ah, r, off);
        a_l[m] = ldfrag(Al, r, off);
      }
#pragma unroll
      for (int n = 0; n < 2; ++n) {
        int r = n * 16 + lp;
        b_h[n] = ldfrag(Bh, r, off);
        b_l[n] = ldfrag(Bl, r, off);
      }
#pragma unroll
      for (int m = 0; m < 2; ++m)
#pragma unroll
        for (int n = 0; n < 2; ++n) {
          acc[m][n] = mfma16(a_h[m], b_h[n], acc[m][n]);
          acc[m][n] = mfma16(a_h[m], b_l[n], acc[m][n]);
          acc[m][n] = mfma16(a_l[m], b_h[n], acc[m][n]);
        }
    }
    __syncthreads();
  }

  // epilogue: lane lp = plane index; cols 0..15 key dots, 16..31 query dots
  float kb = key_b[lp], qb = query_b[lp];
#pragma unroll
  for (int m = 0; m < 2; ++m) {
#pragma unroll
    for (int j = 0; j < 4; ++j) {
      float kd = acc[m][0][j] + kb;
      float qd = acc[m][1][j] + qb;
      float av = cosf((tanhf(kd) - tanhf(qd)) * PI_F);
      av += __shfl_xor(av, 1);
      av += __shfl_xor(av, 2);
      av += __shfl_xor(av, 4);
      av += __shfl_xor(av, 8);
      if (lp == 0) {
        int row = bm * 128 + w * 32 + m * 16 + lhi * 4 + j;
        float res = av * (1.f / 16.f);                    // mean(align)
        float zz = res + 0.5f;
        float gain = fmaxf(zz, 0.f) + log1pf(expf(-fabsf(zz)));  // softplus
        sarr[row] = gain * res;                           // s = gain*sum(align)/16
      }
    }
  }
}

// ---------------- K2 (fast path): V = xh @ Wv^T, pure gload_lds ----------------
__global__ void __launch_bounds__(256) k2_vgemm_f16(
    const f16* __restrict__ xh, const f16* __restrict__ Wv,
    const float* __restrict__ value_b,
    f16* __restrict__ Vh, float* __restrict__ part)
{
  __shared__ __align__(16) f16 Ah[128 * 64];
  __shared__ __align__(16) f16 Bh[128 * 64];
  int t = threadIdx.x;
  int swz = xcd_swz(blockIdx.x, 4096);
  int bn = swz & 7, bm = swz >> 3;
  int w = t >> 6, l = t & 63, lp = l & 15, lhi = l >> 4;
  int wr = w >> 1, wc = w & 1;
  f32x4 z = {0.f, 0.f, 0.f, 0.f};
  f32x4 acc[4][4];
#pragma unroll
  for (int m = 0; m < 4; ++m)
#pragma unroll
    for (int n = 0; n < 4; ++n) acc[m][n] = z;

  for (int kt = 0; kt < 16; ++kt) {
    stage_w(xh, bm * 128, kt, Ah, t, 1024);
    stage_w(Wv, bn * 128, kt, Bh, t, 1024);
    __syncthreads();
#pragma unroll
    for (int kk = 0; kk < 2; ++kk) {
      int off = kk * 32 + lhi * 8;
      f16x8 af[4], bf[4];
#pragma unroll
      for (int m = 0; m < 4; ++m) af[m] = ldfrag(Ah, wr * 64 + m * 16 + lp, off);
#pragma unroll
      for (int n = 0; n < 4; ++n) bf[n] = ldfrag(Bh, wc * 64 + n * 16 + lp, off);
#pragma unroll
      for (int m = 0; m < 4; ++m)
#pragma unroll
        for (int n = 0; n < 4; ++n)
          acc[m][n] = mfma16(af[m], bf[n], acc[m][n]);
    }
    __syncthreads();
  }

  int col0 = bn * 128 + wc * 64;
  float vb[4];
#pragma unroll
  for (int n = 0; n < 4; ++n) vb[n] = value_b[col0 + n * 16 + lp];
#pragma unroll
  for (int m = 0; m < 4; ++m) {
#pragma unroll
    for (int j = 0; j < 4; ++j) {
      int row = bm * 128 + wr * 64 + m * 16 + lhi * 4 + j;
      float sv = 0.f, sq = 0.f;
#pragma unroll
      for (int n = 0; n < 4; ++n) {
        float v = acc[m][n][j] + vb[n];
        Vh[(size_t)row * 1024 + col0 + n * 16 + lp] = (f16)v;
        sv += v; sq += v * v;
      }
      sv += __shfl_xor(sv, 1); sq += __shfl_xor(sq, 1);
      sv += __shfl_xor(sv, 2); sq += __shfl_xor(sq, 2);
      sv += __shfl_xor(sv, 4); sq += __shfl_xor(sq, 4);
      sv += __shfl_xor(sv, 8); sq += __shfl_xor(sq, 8);
      if (lp == 0) {
        size_t idx = ((size_t)row * 16 + bn * 2 + wc) * 2;
        part[idx] = sv;
        part[idx + 1] = sq;
      }
    }
  }
}

// ---------------- K2 (fallback): reg-staged fp32 x, now XCD-swizzled ----------------
__global__ void __launch_bounds__(256) k2_vgemm(
    const float* __restrict__ x, const f16* __restrict__ Wv,
    const float* __restrict__ value_b,
    f16* __restrict__ Vh, float* __restrict__ part)
{
  __shared__ __align__(16) f16 Ah[128 * 64];
  __shared__ __align__(16) f16 Bh[128 * 64];
  int t = threadIdx.x;
  int swz = xcd_swz(blockIdx.x, 4096);
  int bn = swz & 7, bm = swz >> 3;
  int w = t >> 6, l = t & 63, lp = l & 15, lhi = l >> 4;
  int wr = w >> 1, wc = w & 1;
  f32x4 z = {0.f, 0.f, 0.f, 0.f};
  f32x4 acc[4][4];
#pragma unroll
  for (int m = 0; m < 4; ++m)
#pragma unroll
    for (int n = 0; n < 4; ++n) acc[m][n] = z;

  for (int kt = 0; kt < 16; ++kt) {
    stage_x_h(x, bm * 128, kt, Ah, t);
    stage_w(Wv, bn * 128, kt, Bh, t, 1024);
    __syncthreads();
#pragma unroll
    for (int kk = 0; kk < 2; ++kk) {
      int off = kk * 32 + lhi * 8;
      f16x8 af[4], bf[4];
#pragma unroll
      for (int m = 0; m < 4; ++m) af[m] = ldfrag(Ah, wr * 64 + m * 16 + lp, off);
#pragma unroll
      for (int n = 0; n < 4; ++n) bf[n] = ldfrag(Bh, wc * 64 + n * 16 + lp, off);
#pragma unroll
      for (int m = 0; m < 4; ++m)
#pragma unroll
        for (int n = 0; n < 4; ++n)
          acc[m][n] = mfma16(af[m], bf[n], acc[m][n]);
    }
    __syncthreads();
  }

  int col0 = bn * 128 + wc * 64;
  float vb[4];
#pragma unroll
  for (int n = 0; n < 4; ++n) vb[n] = value_b[col0 + n * 16 + lp];
#pragma unroll
  for (int m = 0; m < 4; ++m) {
#pragma unroll
    for (int j = 0; j < 4; ++j) {
      int row = bm * 128 + wr * 64 + m * 16 + lhi * 4 + j;
      float sv = 0.f, sq = 0.f;
#pragma unroll
      for (int n = 0; n < 4; ++n) {
        float v = acc[m][n][j] + vb[n];
        Vh[(size_t)row * 1024 + col0 + n * 16 + lp] = (f16)v;
        sv += v; sq += v * v;
      }
      sv += __shfl_xor(sv, 1); sq += __shfl_xor(sq, 1);
      sv += __shfl_xor(sv, 2); sq += __shfl_xor(sq, 2);
      sv += __shfl_xor(sv, 4); sq += __shfl_xor(sq, 4);
      sv += __shfl_xor(sv, 8); sq += __shfl_xor(sq, 8);
      if (lp == 0) {
        size_t idx = ((size_t)row * 16 + bn * 2 + wc) * 2;
        part[idx] = sv;
        part[idx + 1] = sq;
      }
    }
  }
}

// ---------------- K2b: per-row alpha/beta ----------------
__global__ void __launch_bounds__(256) k2b_ab(
    const float* __restrict__ part, const float* __restrict__ sarr,
    float* __restrict__ alpha, float* __restrict__ beta)
{
  int row = blockIdx.x * 256 + threadIdx.x;
  const float4* p = (const float4*)(part + (size_t)row * 32);
  float sv = 0.f, sq = 0.f;
#pragma unroll
  for (int i = 0; i < 8; ++i) { float4 q = p[i]; sv += q.x + q.z; sq += q.y + q.w; }
  float mu  = sv * (1.f / 1024.f);
  float var = sq * (1.f / 1024.f) - mu * mu;       // row var of V
  float s = sarr[row];
  float tt = rsqrtf(s * s * var + 1e-5f);          // rsqrt(var_P + eps), var_P = s^2 var_V
  float a = s * tt;
  alpha[row] = a;
  beta[row]  = -a * mu;
}

// ---------------- K3: out = x + alpha*(Vh @ Wo^T) + beta*c1 + c2 ----------------
__global__ void __launch_bounds__(256) k3_out(
    const f16* __restrict__ Vh, const f16* __restrict__ Wo,
    const float* __restrict__ x,
    const float* __restrict__ alpha, const float* __restrict__ beta,
    const float* __restrict__ c1, const float* __restrict__ c2,
    float* __restrict__ out)
{
  __shared__ __align__(16) f16 Ah[128 * 64];
  __shared__ __align__(16) f16 Bh[128 * 64];
  int t = threadIdx.x;
  int swz = xcd_swz(blockIdx.x, 4096);
  int bn = swz & 7, bm = swz >> 3;
  int w = t >> 6, l = t & 63, lp = l & 15, lhi = l >> 4;
  int wr = w >> 1, wc = w & 1;
  f32x4 z = {0.f, 0.f, 0.f, 0.f};
  f32x4 acc[4][4];
#pragma unroll
  for (int m = 0; m < 4; ++m)
#pragma unroll
    for (int n = 0; n < 4; ++n) acc[m][n] = z;

  for (int kt = 0; kt < 16; ++kt) {
    stage_w(Vh, bm * 128, kt, Ah, t, 1024);
    stage_w(Wo, bn * 128, kt, Bh, t, 1024);
    __syncthreads();
#pragma unroll
    for (int kk = 0; kk < 2; ++kk) {
      int off = kk * 32 + lhi * 8;
      f16x8 af[4], bf[4];
#pragma unroll
      for (int m = 0; m < 4; ++m) af[m] = ldfrag(Ah, wr * 64 + m * 16 + lp, off);
#pragma unroll
      for (int n = 0; n < 4; ++n) bf[n] = ldfrag(Bh, wc * 64 + n * 16 + lp, off);
#pragma unroll
      for (int m = 0; m < 4; ++m)
#pragma unroll
        for (int n = 0; n < 4; ++n)
          acc[m][n] = mfma16(af[m], bf[n], acc[m][n]);
    }
    __syncthreads();
  }

  int col0 = bn * 128 + wc * 64;
  float c1v[4], c2v[4];
#pragma unroll
  for (int n = 0; n < 4; ++n) {
    c1v[n] = c1[col0 + n * 16 + lp];
    c2v[n] = c2[col0 + n * 16 + lp];
  }
#pragma unroll
  for (int m = 0; m < 4; ++m) {
#pragma unroll
    for (int j = 0; j < 4; ++j) {
      int row = bm * 128 + wr * 64 + m * 16 + lhi * 4 + j;
      float av = alpha[row], bv = beta[row];
      const float* xr = x + (size_t)row * 1024;
      float* orow = out + (size_t)row * 1024;
#pragma unroll
      for (int n = 0; n < 4; ++n) {
        int c = col0 + n * 16 + lp;
        orow[c] = xr[c] + av * acc[m][n][j] + bv * c1v[n] + c2v[n];
      }
    }
  }
}

// ---------------- launch ----------------
extern "C" void kernel_launch(void* const* d_in, const int* in_sizes, int n_in,
                              void* d_out, int out_size, void* d_ws, size_t ws_size,
                              hipStream_t stream)
{
  const float* x       = (const float*)d_in[0];
  const float* key_W   = (const float*)d_in[1];
  const float* key_b   = (const float*)d_in[2];
  const float* query_W = (const float*)d_in[3];
  const float* query_b = (const float*)d_in[4];
  const float* value_W = (const float*)d_in[5];
  const float* value_b = (const float*)d_in[6];
  const float* ln_g    = (const float*)d_in[7];
  const float* ln_b    = (const float*)d_in[8];
  const float* out_W   = (const float*)d_in[9];
  const float* out_b   = (const float*)d_in[10];
  float* out = (float*)d_out;

  // workspace layout (272 MB with xh; 144 MB without)
  char* ws = (char*)d_ws;
  f16*   Wv    = (f16*)(ws);                                  //   2 MB
  f16*   Wo    = (f16*)(ws + (2u << 20));                     //   2 MB (g-folded)
  f16*   kqh   = (f16*)(ws + (4u << 20));                     //  64 KB
  f16*   kql   = (f16*)(ws + (4u << 20) + (64u << 10));       //  64 KB
  float* c1    = (float*)(ws + (4u << 20) + (128u << 10));    //   4 KB
  float* c2    = (float*)(ws + (4u << 20) + (132u << 10));    //   4 KB
  float* sarr  = (float*)(ws + (5u << 20));                   // 256 KB
  float* alpha = (float*)(ws + (5u << 20) + (256u << 10));    // 256 KB
  float* beta  = (float*)(ws + (5u << 20) + (512u << 10));    // 256 KB
  float* part  = (float*)(ws + (6u << 20));                   //   8 MB
  f16*   Vh    = (f16*)(ws + (16u << 20));                    // 128 MB
  f16*   xh    = (f16*)(ws + (144u << 20));                   // 128 MB (fast path)

  bool big_ws = ws_size >= (272ull << 20);
  f16* xh_out = big_ws ? xh : nullptr;

  k0_prep<<<dim3(1056), dim3(256), 0, stream>>>(value_W, out_W, key_W, query_W,
                                                ln_g, ln_b, out_b,
                                                Wv, Wo, kqh, kql, c1, c2);
  k1_kq<<<dim3(512), dim3(256), 0, stream>>>(x, xh_out, kqh, kql, key_b, query_b, sarr);
  if (big_ws) {
    k2_vgemm_f16<<<dim3(4096), dim3(256), 0, stream>>>(xh, Wv, value_b, Vh, part);
  } else {
    k2_vgemm<<<dim3(4096), dim3(256), 0, stream>>>(x, Wv, value_b, Vh, part);
  }
  k2b_ab<<<dim3(256), dim3(256), 0, stream>>>(part, sarr, alpha, beta);
  k3_out<<<dim3(4096), dim3(256), 0, stream>>>(Vh, Wo, x, alpha, beta, c1, c2, out);
}

// Round 8
// 971.473 us; speedup vs baseline: 1.1035x; 1.0300x over previous
//
#include <hip/hip_runtime.h>
#include <cstdint>
#include <cstddef>

// PhasorLayerLinear fused pipeline for MI355X (gfx950).
//
//   K0 : weight prep  (value_W -> f16; g-folded out_W -> f16; key/query W -> f16 hi/lo; c1,c2)
//   K1 : kq phases    (3-pass hi/lo f16 MFMA) -> s[row]; ALSO emits xh = f16(x) byproduct
//   K2 : V = xh @ Wv^T (gload_lds + 2-phase dbuf pipeline)
//   K2b: per-row alpha/beta from s + stats   (LN folded into scalars)
//   K3 : out = x + alpha*(Vh @ (g.out_W)^T) + beta*c1 + c2  (same pipeline)
//
// R4 post-mortem: all three big kernels ~300us, latency-bound quadrant
// (MfmaUtil 18%, HBM 22%, occ 22%): per-K-step vmcnt(0)+__syncthreads drain
// exposes L3/HBM latency (~600-900cy) serially with only ~2 blocks/CU TLP.
// R5 fix: T3-minimum 2-phase dbuf — stage(t+1) issued BEFORE compute(t), raw
// s_barrier + explicit waitcnt asm (NOT __syncthreads, which re-inserts the
// drain), one barrier per K-step. K1 uses the T14 split (loads->regs early,
// cvt+ds_write late) since its A-path converts fp32->f16 hi/lo.
// (R5-R7 never ran — GPU timeouts; resubmitted after three race re-audits.)

typedef _Float16 f16;
typedef _Float16 f16x4 __attribute__((ext_vector_type(4)));
typedef _Float16 f16x8 __attribute__((ext_vector_type(8)));
typedef float    f32x4 __attribute__((ext_vector_type(4)));

#define PI_F 3.14159265358979323846f

// CK-style address-space bridging (integer round-trip is always legal).
typedef const __attribute__((address_space(1))) void* gptr_t;
typedef __attribute__((address_space(3))) void* lptr_t;

__device__ __forceinline__ void gld16(const void* g, void* l) {
  __builtin_amdgcn_global_load_lds((gptr_t)(uintptr_t)g, (lptr_t)(uint32_t)(uintptr_t)l,
                                   16, 0, 0);
}

__device__ __forceinline__ f32x4 mfma16(f16x8 a, f16x8 b, f32x4 c) {
  return __builtin_amdgcn_mfma_f32_16x16x32_f16(a, b, c, 0, 0, 0);
}

// LDS tile is [rows][64] f16, row-major. off = kk*32 + (lane>>4)*8.
__device__ __forceinline__ f16x8 ldfrag(const f16* L, int row, int off) {
  return *(const f16x8*)(L + row * 64 + off);
}

// chunked XCD swizzle (nwg % 8 == 0): XCD (bid%8) owns a contiguous swz chunk;
// runs of 8 swz values share bm (one A-panel) and sweep all 8 bn col-blocks.
__device__ __forceinline__ int xcd_swz(int bid, int nwg) {
  return (bid & 7) * (nwg >> 3) + (bid >> 3);
}

// drain + raw barrier (NO __syncthreads in the pipelined loops: hipcc emits
// s_waitcnt vmcnt(0) before s_barrier for __syncthreads, which would drain the
// prefetch and serialize the pipeline — the m97 ~20% stall mechanism).
#define DRAIN_ALL() asm volatile("s_waitcnt vmcnt(0) lgkmcnt(0)" ::: "memory")
#define SCHED_FENCE() __builtin_amdgcn_sched_barrier(0)
#define BAR() __builtin_amdgcn_s_barrier()

// ---------------- K0: weight prep ----------------
__global__ void __launch_bounds__(256) k0_prep(
    const float* __restrict__ value_W, const float* __restrict__ out_W,
    const float* __restrict__ key_W,   const float* __restrict__ query_W,
    const float* __restrict__ ln_g,    const float* __restrict__ ln_b,
    const float* __restrict__ out_b,
    f16* __restrict__ Wv, f16* __restrict__ Wo,
    f16* __restrict__ kqh, f16* __restrict__ kql,
    float* __restrict__ c1, float* __restrict__ c2)
{
  __shared__ float r1[256];
  __shared__ float r2[256];
  int t = threadIdx.x;
  int blk = blockIdx.x;
  if (blk < 1024) {
    int n = blk;
    float4 v = ((const float4*)(value_W + (size_t)n * 1024))[t];
    float4 o = ((const float4*)(out_W   + (size_t)n * 1024))[t];
    float4 g = ((const float4*)ln_g)[t];
    float4 b = ((const float4*)ln_b)[t];
    f16x4 vh = {(f16)v.x, (f16)v.y, (f16)v.z, (f16)v.w};
    ((f16x4*)(Wv + (size_t)n * 1024))[t] = vh;
    float gx = o.x * g.x, gy = o.y * g.y, gz = o.z * g.z, gw = o.w * g.w;
    f16x4 oh = {(f16)gx, (f16)gy, (f16)gz, (f16)gw};
    ((f16x4*)(Wo + (size_t)n * 1024))[t] = oh;
    r1[t] = gx + gy + gz + gw;                                // sum g_k * Wo[n][k]
    r2[t] = o.x*b.x + o.y*b.y + o.z*b.z + o.w*b.w;            // sum b_k * Wo[n][k]
    __syncthreads();
    for (int off = 128; off > 0; off >>= 1) {
      if (t < off) { r1[t] += r1[t + off]; r2[t] += r2[t + off]; }
      __syncthreads();
    }
    if (t == 0) { c1[n] = r1[0]; c2[n] = r2[0] + out_b[n]; }
  } else {
    int r = blk - 1024;  // 0..15 key planes, 16..31 query planes
    const float* src = (r < 16) ? (key_W + (size_t)r * 1024)
                                : (query_W + (size_t)(r - 16) * 1024);
    float4 v = ((const float4*)src)[t];
    f16 h0 = (f16)v.x, h1 = (f16)v.y, h2 = (f16)v.z, h3 = (f16)v.w;
    f16x4 hv = {h0, h1, h2, h3};
    f16x4 lv = {(f16)(v.x - (float)h0), (f16)(v.y - (float)h1),
                (f16)(v.z - (float)h2), (f16)(v.w - (float)h3)};
    ((f16x4*)(kqh + (size_t)r * 1024))[t] = hv;
    ((f16x4*)(kql + (size_t)r * 1024))[t] = lv;
  }
}

// ---------------- staging helpers ----------------
// reg-stage 128x64 fp32 x tile -> f16 hi LDS tile (fallback path only)
__device__ __forceinline__ void stage_x_h(const float* __restrict__ xg, int row0, int kt,
                                          f16* Ah, int t)
{
  const float* base = xg + (size_t)row0 * 1024 + kt * 64;
#pragma unroll
  for (int it = 0; it < 8; ++it) {
    int cf = it * 256 + t;
    int r = cf >> 4, ci = cf & 15;
    float4 v = *(const float4*)(base + (size_t)r * 1024 + ci * 4);
    f16x4 h = {(f16)v.x, (f16)v.y, (f16)v.z, (f16)v.w};
    *(f16x4*)(Ah + r * 64 + ci * 4) = h;
  }
}

// async-stage an [nrows x 64] f16 tile (global row stride 1024) via global_load_lds w=16
// LDS dest is linear in thread id => wave-uniform base + lane*16B (HW requirement).
__device__ __forceinline__ void stage_w(const f16* __restrict__ wg, int n0, int kt,
                                        f16* Bt, int t, int nchunk)
{
  for (int c = t; c < nchunk; c += 256) {
    int r = c >> 3, ci = c & 7;
    gld16(wg + (size_t)(n0 + r) * 1024 + kt * 64 + ci * 8, Bt + c * 8);
  }
}

// ---------------- K1: key/query phases -> s[row] (+ xh byproduct) ----------------
// 3-pass hi/lo split (a_h*b_h + a_h*b_l + a_l*b_h): the rsqrt(eps) knife-edge
// amplifies s-errors by up to ~316x, so the phase dots need ~1e-5 accuracy.
// Pipeline: loads(t+1)->regs + B gld16(t+1) issued BEFORE compute(t);
// cvt+ds_write(t+1) after compute; one raw barrier per step.
__global__ void __launch_bounds__(256) k1_kq(
    const float* __restrict__ x, f16* __restrict__ xh_out,
    const f16* __restrict__ kqh, const f16* __restrict__ kql,
    const float* __restrict__ key_b, const float* __restrict__ query_b,
    float* __restrict__ sarr)
{
  __shared__ __align__(16) f16 Ah[2][128 * 64];
  __shared__ __align__(16) f16 Al[2][128 * 64];
  __shared__ __align__(16) f16 Bh[2][32 * 64];
  __shared__ __align__(16) f16 Bl[2][32 * 64];
  int t = threadIdx.x, bm = blockIdx.x;
  int w = t >> 6, l = t & 63, lp = l & 15, lhi = l >> 4;
  f32x4 z = {0.f, 0.f, 0.f, 0.f};
  f32x4 acc[2][2];
  acc[0][0] = z; acc[0][1] = z; acc[1][0] = z; acc[1][1] = z;

  const float* xbase = x + (size_t)bm * 128 * 1024;
  f16* obase = xh_out ? (xh_out + (size_t)bm * 128 * 1024) : nullptr;
  float4 xv[8];

  // prologue: tile 0 staged synchronously
#pragma unroll
  for (int it = 0; it < 8; ++it) {
    int cf = it * 256 + t, r = cf >> 4, ci = cf & 15;
    xv[it] = *(const float4*)(xbase + (size_t)r * 1024 + ci * 4);
  }
  stage_w(kqh, 0, 0, &Bh[0][0], t, 256);
  stage_w(kql, 0, 0, &Bl[0][0], t, 256);
#pragma unroll
  for (int it = 0; it < 8; ++it) {
    int cf = it * 256 + t, r = cf >> 4, ci = cf & 15;
    float4 v = xv[it];
    f16 h0 = (f16)v.x, h1 = (f16)v.y, h2 = (f16)v.z, h3 = (f16)v.w;
    f16x4 hv = {h0, h1, h2, h3};
    f16x4 lv = {(f16)(v.x - (float)h0), (f16)(v.y - (float)h1),
                (f16)(v.z - (float)h2), (f16)(v.w - (float)h3)};
    *(f16x4*)(&Ah[0][0] + r * 64 + ci * 4) = hv;
    *(f16x4*)(&Al[0][0] + r * 64 + ci * 4) = lv;
    if (obase) *(f16x4*)(obase + (size_t)r * 1024 + ci * 4) = hv;
  }
  DRAIN_ALL();
  SCHED_FENCE();
  BAR();

  int cur = 0;
  for (int kt = 0; kt < 16; ++kt) {
    bool pf = kt < 15;
    if (pf) {
      const float* bn_ = xbase + (kt + 1) * 64;
#pragma unroll
      for (int it = 0; it < 8; ++it) {
        int cf = it * 256 + t, r = cf >> 4, ci = cf & 15;
        xv[it] = *(const float4*)(bn_ + (size_t)r * 1024 + ci * 4);
      }
      stage_w(kqh, 0, kt + 1, &Bh[cur ^ 1][0], t, 256);
      stage_w(kql, 0, kt + 1, &Bl[cur ^ 1][0], t, 256);
    }
    const f16* AHc = &Ah[cur][0]; const f16* ALc = &Al[cur][0];
    const f16* BHc = &Bh[cur][0]; const f16* BLc = &Bl[cur][0];
#pragma unroll
    for (int kk = 0; kk < 2; ++kk) {
      int off = kk * 32 + lhi * 8;
      f16x8 a_h[2], a_l[2], b_h[2], b_l[2];
#pragma unroll
      for (int m = 0; m < 2; ++m) {
        int r = w * 32 + m * 16 + lp;
        a_h[m] = ldfrag(AHc, r, off);
        a_l[m] = ldfrag(ALc, r, off);
      }
#pragma unroll
      for (int n = 0; n < 2; ++n) {
        int r = n * 16 + lp;
        b_h[n] = ldfrag(BHc, r, off);
        b_l[n] = ldfrag(BLc, r, off);
      }
#pragma unroll
      for (int m = 0; m < 2; ++m)
#pragma unroll
        for (int n = 0; n < 2; ++n) {
          acc[m][n] = mfma16(a_h[m], b_h[n], acc[m][n]);
          acc[m][n] = mfma16(a_h[m], b_l[n], acc[m][n]);
          acc[m][n] = mfma16(a_l[m], b_h[n], acc[m][n]);
        }
    }
    if (pf) {
      // T14 write-late: cvt + ds_write into the other buffer (last read 2 steps ago)
      f16* ah = &Ah[cur ^ 1][0]; f16* al = &Al[cur ^ 1][0];
      f16* ob = obase ? obase + (kt + 1) * 64 : nullptr;
#pragma unroll
      for (int it = 0; it < 8; ++it) {
        int cf = it * 256 + t, r = cf >> 4, ci = cf & 15;
        float4 v = xv[it];
        f16 h0 = (f16)v.x, h1 = (f16)v.y, h2 = (f16)v.z, h3 = (f16)v.w;
        f16x4 hv = {h0, h1, h2, h3};
        f16x4 lv = {(f16)(v.x - (float)h0), (f16)(v.y - (float)h1),
                    (f16)(v.z - (float)h2), (f16)(v.w - (float)h3)};
        *(f16x4*)(ah + r * 64 + ci * 4) = hv;
        *(f16x4*)(al + r * 64 + ci * 4) = lv;
        if (ob) *(f16x4*)(ob + (size_t)r * 1024 + ci * 4) = hv;
      }
      DRAIN_ALL();
      SCHED_FENCE();
    }
    BAR();
    cur ^= 1;
  }

  // epilogue: lane lp = plane index; cols 0..15 key dots, 16..31 query dots
  float kb = key_b[lp], qb = query_b[lp];
#pragma unroll
  for (int m = 0; m < 2; ++m) {
#pragma unroll
    for (int j = 0; j < 4; ++j) {
      float kd = acc[m][0][j] + kb;
      float qd = acc[m][1][j] + qb;
      float av = cosf((tanhf(kd) - tanhf(qd)) * PI_F);
      av += __shfl_xor(av, 1);
      av += __shfl_xor(av, 2);
      av += __shfl_xor(av, 4);
      av += __shfl_xor(av, 8);
      if (lp == 0) {
        int row = bm * 128 + w * 32 + m * 16 + lhi * 4 + j;
        float res = av * (1.f / 16.f);                    // mean(align)
        float zz = res + 0.5f;
        float gain = fmaxf(zz, 0.f) + log1pf(expf(-fabsf(zz)));  // softplus
        sarr[row] = gain * res;                           // s = gain*sum(align)/16
      }
    }
  }
}

// ---------------- K2 (fast path): V = xh @ Wv^T, gload_lds 2-phase dbuf ----------------
__global__ void __launch_bounds__(256) k2_vgemm_f16(
    const f16* __restrict__ xh, const f16* __restrict__ Wv,
    const float* __restrict__ value_b,
    f16* __restrict__ Vh, float* __restrict__ part)
{
  __shared__ __align__(16) f16 A2[2][128 * 64];
  __shared__ __align__(16) f16 B2[2][128 * 64];
  int t = threadIdx.x;
  int swz = xcd_swz(blockIdx.x, 4096);
  int bn = swz & 7, bm = swz >> 3;
  int w = t >> 6, l = t & 63, lp = l & 15, lhi = l >> 4;
  int wr = w >> 1, wc = w & 1;
  f32x4 z = {0.f, 0.f, 0.f, 0.f};
  f32x4 acc[4][4];
#pragma unroll
  for (int m = 0; m < 4; ++m)
#pragma unroll
    for (int n = 0; n < 4; ++n) acc[m][n] = z;

  stage_w(xh, bm * 128, 0, &A2[0][0], t, 1024);
  stage_w(Wv, bn * 128, 0, &B2[0][0], t, 1024);
  DRAIN_ALL();
  SCHED_FENCE();
  BAR();

  int cur = 0;
  for (int kt = 0; kt < 16; ++kt) {
    if (kt < 15) {
      stage_w(xh, bm * 128, kt + 1, &A2[cur ^ 1][0], t, 1024);
      stage_w(Wv, bn * 128, kt + 1, &B2[cur ^ 1][0], t, 1024);
    }
    const f16* Ac = &A2[cur][0]; const f16* Bc = &B2[cur][0];
#pragma unroll
    for (int kk = 0; kk < 2; ++kk) {
      int off = kk * 32 + lhi * 8;
      f16x8 af[4], bf[4];
#pragma unroll
      for (int m = 0; m < 4; ++m) af[m] = ldfrag(Ac, wr * 64 + m * 16 + lp, off);
#pragma unroll
      for (int n = 0; n < 4; ++n) bf[n] = ldfrag(Bc, wc * 64 + n * 16 + lp, off);
#pragma unroll
      for (int m = 0; m < 4; ++m)
#pragma unroll
        for (int n = 0; n < 4; ++n)
          acc[m][n] = mfma16(af[m], bf[n], acc[m][n]);
    }
    DRAIN_ALL();   // prefetch landed + all ds_reads of cur complete
    SCHED_FENCE();
    BAR();
    cur ^= 1;
  }

  int col0 = bn * 128 + wc * 64;
  float vb[4];
#pragma unroll
  for (int n = 0; n < 4; ++n) vb[n] = value_b[col0 + n * 16 + lp];
#pragma unroll
  for (int m = 0; m < 4; ++m) {
#pragma unroll
    for (int j = 0; j < 4; ++j) {
      int row = bm * 128 + wr * 64 + m * 16 + lhi * 4 + j;
      float sv = 0.f, sq = 0.f;
#pragma unroll
      for (int n = 0; n < 4; ++n) {
        float v = acc[m][n][j] + vb[n];
        Vh[(size_t)row * 1024 + col0 + n * 16 + lp] = (f16)v;
        sv += v; sq += v * v;
      }
      sv += __shfl_xor(sv, 1); sq += __shfl_xor(sq, 1);
      sv += __shfl_xor(sv, 2); sq += __shfl_xor(sq, 2);
      sv += __shfl_xor(sv, 4); sq += __shfl_xor(sq, 4);
      sv += __shfl_xor(sv, 8); sq += __shfl_xor(sq, 8);
      if (lp == 0) {
        size_t idx = ((size_t)row * 16 + bn * 2 + wc) * 2;
        part[idx] = sv;
        part[idx + 1] = sq;
      }
    }
  }
}

// ---------------- K2 (fallback): reg-staged fp32 x, XCD-swizzled ----------------
__global__ void __launch_bounds__(256) k2_vgemm(
    const float* __restrict__ x, const f16* __restrict__ Wv,
    const float* __restrict__ value_b,
    f16* __restrict__ Vh, float* __restrict__ part)
{
  __shared__ __align__(16) f16 Ah[128 * 64];
  __shared__ __align__(16) f16 Bh[128 * 64];
  int t = threadIdx.x;
  int swz = xcd_swz(blockIdx.x, 4096);
  int bn = swz & 7, bm = swz >> 3;
  int w = t >> 6, l = t & 63, lp = l & 15, lhi = l >> 4;
  int wr = w >> 1, wc = w & 1;
  f32x4 z = {0.f, 0.f, 0.f, 0.f};
  f32x4 acc[4][4];
#pragma unroll
  for (int m = 0; m < 4; ++m)
#pragma unroll
    for (int n = 0; n < 4; ++n) acc[m][n] = z;

  for (int kt = 0; kt < 16; ++kt) {
    stage_x_h(x, bm * 128, kt, Ah, t);
    stage_w(Wv, bn * 128, kt, Bh, t, 1024);
    __syncthreads();
#pragma unroll
    for (int kk = 0; kk < 2; ++kk) {
      int off = kk * 32 + lhi * 8;
      f16x8 af[4], bf[4];
#pragma unroll
      for (int m = 0; m < 4; ++m) af[m] = ldfrag(Ah, wr * 64 + m * 16 + lp, off);
#pragma unroll
      for (int n = 0; n < 4; ++n) bf[n] = ldfrag(Bh, wc * 64 + n * 16 + lp, off);
#pragma unroll
      for (int m = 0; m < 4; ++m)
#pragma unroll
        for (int n = 0; n < 4; ++n)
          acc[m][n] = mfma16(af[m], bf[n], acc[m][n]);
    }
    __syncthreads();
  }

  int col0 = bn * 128 + wc * 64;
  float vb[4];
#pragma unroll
  for (int n = 0; n < 4; ++n) vb[n] = value_b[col0 + n * 16 + lp];
#pragma unroll
  for (int m = 0; m < 4; ++m) {
#pragma unroll
    for (int j = 0; j < 4; ++j) {
      int row = bm * 128 + wr * 64 + m * 16 + lhi * 4 + j;
      float sv = 0.f, sq = 0.f;
#pragma unroll
      for (int n = 0; n < 4; ++n) {
        float v = acc[m][n][j] + vb[n];
        Vh[(size_t)row * 1024 + col0 + n * 16 + lp] = (f16)v;
        sv += v; sq += v * v;
      }
      sv += __shfl_xor(sv, 1); sq += __shfl_xor(sq, 1);
      sv += __shfl_xor(sv, 2); sq += __shfl_xor(sq, 2);
      sv += __shfl_xor(sv, 4); sq += __shfl_xor(sq, 4);
      sv += __shfl_xor(sv, 8); sq += __shfl_xor(sq, 8);
      if (lp == 0) {
        size_t idx = ((size_t)row * 16 + bn * 2 + wc) * 2;
        part[idx] = sv;
        part[idx + 1] = sq;
      }
    }
  }
}

// ---------------- K2b: per-row alpha/beta ----------------
__global__ void __launch_bounds__(256) k2b_ab(
    const float* __restrict__ part, const float* __restrict__ sarr,
    float* __restrict__ alpha, float* __restrict__ beta)
{
  int row = blockIdx.x * 256 + threadIdx.x;
  const float4* p = (const float4*)(part + (size_t)row * 32);
  float sv = 0.f, sq = 0.f;
#pragma unroll
  for (int i = 0; i < 8; ++i) { float4 q = p[i]; sv += q.x + q.z; sq += q.y + q.w; }
  float mu  = sv * (1.f / 1024.f);
  float var = sq * (1.f / 1024.f) - mu * mu;       // row var of V
  float s = sarr[row];
  float tt = rsqrtf(s * s * var + 1e-5f);          // rsqrt(var_P + eps), var_P = s^2 var_V
  float a = s * tt;
  alpha[row] = a;
  beta[row]  = -a * mu;
}

// ---------------- K3: out = x + alpha*(Vh @ Wo^T) + beta*c1 + c2 ----------------
__global__ void __launch_bounds__(256) k3_out(
    const f16* __restrict__ Vh, const f16* __restrict__ Wo,
    const float* __restrict__ x,
    const float* __restrict__ alpha, const float* __restrict__ beta,
    const float* __restrict__ c1, const float* __restrict__ c2,
    float* __restrict__ out)
{
  __shared__ __align__(16) f16 A2[2][128 * 64];
  __shared__ __align__(16) f16 B2[2][128 * 64];
  int t = threadIdx.x;
  int swz = xcd_swz(blockIdx.x, 4096);
  int bn = swz & 7, bm = swz >> 3;
  int w = t >> 6, l = t & 63, lp = l & 15, lhi = l >> 4;
  int wr = w >> 1, wc = w & 1;
  f32x4 z = {0.f, 0.f, 0.f, 0.f};
  f32x4 acc[4][4];
#pragma unroll
  for (int m = 0; m < 4; ++m)
#pragma unroll
    for (int n = 0; n < 4; ++n) acc[m][n] = z;

  stage_w(Vh, bm * 128, 0, &A2[0][0], t, 1024);
  stage_w(Wo, bn * 128, 0, &B2[0][0], t, 1024);
  DRAIN_ALL();
  SCHED_FENCE();
  BAR();

  int cur = 0;
  for (int kt = 0; kt < 16; ++kt) {
    if (kt < 15) {
      stage_w(Vh, bm * 128, kt + 1, &A2[cur ^ 1][0], t, 1024);
      stage_w(Wo, bn * 128, kt + 1, &B2[cur ^ 1][0], t, 1024);
    }
    const f16* Ac = &A2[cur][0]; const f16* Bc = &B2[cur][0];
#pragma unroll
    for (int kk = 0; kk < 2; ++kk) {
      int off = kk * 32 + lhi * 8;
      f16x8 af[4], bf[4];
#pragma unroll
      for (int m = 0; m < 4; ++m) af[m] = ldfrag(Ac, wr * 64 + m * 16 + lp, off);
#pragma unroll
      for (int n = 0; n < 4; ++n) bf[n] = ldfrag(Bc, wc * 64 + n * 16 + lp, off);
#pragma unroll
      for (int m = 0; m < 4; ++m)
#pragma unroll
        for (int n = 0; n < 4; ++n)
          acc[m][n] = mfma16(af[m], bf[n], acc[m][n]);
    }
    DRAIN_ALL();
    SCHED_FENCE();
    BAR();
    cur ^= 1;
  }

  int col0 = bn * 128 + wc * 64;
  float c1v[4], c2v[4];
#pragma unroll
  for (int n = 0; n < 4; ++n) {
    c1v[n] = c1[col0 + n * 16 + lp];
    c2v[n] = c2[col0 + n * 16 + lp];
  }
#pragma unroll
  for (int m = 0; m < 4; ++m) {
#pragma unroll
    for (int j = 0; j < 4; ++j) {
      int row = bm * 128 + wr * 64 + m * 16 + lhi * 4 + j;
      float av = alpha[row], bv = beta[row];
      const float* xr = x + (size_t)row * 1024;
      float* orow = out + (size_t)row * 1024;
#pragma unroll
      for (int n = 0; n < 4; ++n) {
        int c = col0 + n * 16 + lp;
        orow[c] = xr[c] + av * acc[m][n][j] + bv * c1v[n] + c2v[n];
      }
    }
  }
}

// ---------------- launch ----------------
extern "C" void kernel_launch(void* const* d_in, const int* in_sizes, int n_in,
                              void* d_out, int out_size, void* d_ws, size_t ws_size,
                              hipStream_t stream)
{
  const float* x       = (const float*)d_in[0];
  const float* key_W   = (const float*)d_in[1];
  const float* key_b   = (const float*)d_in[2];
  const float* query_W = (const float*)d_in[3];
  const float* query_b = (const float*)d_in[4];
  const float* value_W = (const float*)d_in[5];
  const float* value_b = (const float*)d_in[6];
  const float* ln_g    = (const float*)d_in[7];
  const float* ln_b    = (const float*)d_in[8];
  const float* out_W   = (const float*)d_in[9];
  const float* out_b   = (const float*)d_in[10];
  float* out = (float*)d_out;

  // workspace layout (272 MB with xh; 144 MB without)
  char* ws = (char*)d_ws;
  f16*   Wv    = (f16*)(ws);                                  //   2 MB
  f16*   Wo    = (f16*)(ws + (2u << 20));                     //   2 MB (g-folded)
  f16*   kqh   = (f16*)(ws + (4u << 20));                     //  64 KB
  f16*   kql   = (f16*)(ws + (4u << 20) + (64u << 10));       //  64 KB
  float* c1    = (float*)(ws + (4u << 20) + (128u << 10));    //   4 KB
  float* c2    = (float*)(ws + (4u << 20) + (132u << 10));    //   4 KB
  float* sarr  = (float*)(ws + (5u << 20));                   // 256 KB
  float* alpha = (float*)(ws + (5u << 20) + (256u << 10));    // 256 KB
  float* beta  = (float*)(ws + (5u << 20) + (512u << 10));    // 256 KB
  float* part  = (float*)(ws + (6u << 20));                   //   8 MB
  f16*   Vh    = (f16*)(ws + (16u << 20));                    // 128 MB
  f16*   xh    = (f16*)(ws + (144u << 20));                   // 128 MB (fast path)

  bool big_ws = ws_size >= (272ull << 20);
  f16* xh_out = big_ws ? xh : nullptr;

  k0_prep<<<dim3(1056), dim3(256), 0, stream>>>(value_W, out_W, key_W, query_W,
                                                ln_g, ln_b, out_b,
                                                Wv, Wo, kqh, kql, c1, c2);
  k1_kq<<<dim3(512), dim3(256), 0, stream>>>(x, xh_out, kqh, kql, key_b, query_b, sarr);
  if (big_ws) {
    k2_vgemm_f16<<<dim3(4096), dim3(256), 0, stream>>>(xh, Wv, value_b, Vh, part);
  } else {
    k2_vgemm<<<dim3(4096), dim3(256), 0, stream>>>(x, Wv, value_b, Vh, part);
  }
  k2b_ab<<<dim3(256), dim3(256), 0, stream>>>(part, sarr, alpha, beta);
  k3_out<<<dim3(4096), dim3(256), 0, stream>>>(Vh, Wo, x, alpha, beta, c1, c2, out);
}